// Round 11
// baseline (509.320 us; speedup 1.0000x reference)
//
#include <hip/hip_runtime.h>
#include <hip/hip_bf16.h>
#include <math.h>

// Problem constants (fixed by setup_inputs)
constexpr int B_ = 2;
constexpr int T_ = 2048;
constexpr int C_ = 1024;
constexpr int H_ = 16;
constexpr int D_ = 64;       // head dim
constexpr int M_ = B_ * T_;  // 4096 rows
constexpr float SHIFT_ = 5.0f;
constexpr float P_MIN_ = 1e-4f;
constexpr float P_MAX_ = 1e3f;
constexpr float V_MIN_ = 1e-10f;
// Q is pre-scaled by log2e/8 in the GEMM epilogue; P = exp2(s) directly.
// Any uniform factor on P cancels exactly in mean = (P@V)/(P@1).
constexpr float QS_ = 0.125f * 1.4426950408889634f;

typedef __attribute__((ext_vector_type(8))) short s16x8;
typedef __attribute__((ext_vector_type(8))) _Float16 h16x8;
typedef __attribute__((ext_vector_type(4))) float f32x4;
typedef unsigned short ushort_t;

__device__ __forceinline__ float clamp_p(float pp) {
    float s = (pp >= 0.f) ? 1.f : -1.f;
    return s * fminf(fmaxf(fabsf(pp), P_MIN_), P_MAX_);
}

// fp32 <-> fp16 bits (RTNE)
__device__ __forceinline__ ushort_t f2h(float f) {
    _Float16 h = (_Float16)f;
    return __builtin_bit_cast(unsigned short, h);
}
__device__ __forceinline__ float h2f(ushort_t h) {
    return (float)__builtin_bit_cast(_Float16, h);
}

// 2^x via v_exp_f32
__device__ __forceinline__ float fast_exp2(float x) {
#if __has_builtin(__builtin_amdgcn_exp2f)
    return __builtin_amdgcn_exp2f(x);
#else
    return __expf(x * 0.6931471805599453f);
#endif
}

// async global->LDS, 16B per lane. LDS dest must be (wave-uniform base + lane*16).
__device__ __forceinline__ void gload_lds16(const void* g, void* l) {
    __builtin_amdgcn_global_load_lds(
        (const __attribute__((address_space(1))) unsigned int*)g,
        (__attribute__((address_space(3))) unsigned int*)l, 16, 0, 0);
}

// ---------------------------------------------------------------------------
// prep_w: fused input prep -- x -> fp16 (blocks 0..4095), w_attn transpose
// (blocks 4096..4863), w_proj transpose (blocks 4864..5119).
// ---------------------------------------------------------------------------
__device__ __forceinline__ void convT_body(const float* __restrict__ W,
                                           ushort_t* __restrict__ Wth,
                                           int N, int K, int bx, int by,
                                           int tid, float (*tile)[65]) {
    const int k0 = by * 64, n0 = bx * 64;
    const int tr = tid >> 4;
    const int tc4 = (tid & 15) * 4;
#pragma unroll
    for (int i = 0; i < 4; ++i) {
        float4 f = *(const float4*)&W[(size_t)(k0 + tr + i * 16) * N + n0 + tc4];
        tile[tr + i * 16][tc4 + 0] = f.x;
        tile[tr + i * 16][tc4 + 1] = f.y;
        tile[tr + i * 16][tc4 + 2] = f.z;
        tile[tr + i * 16][tc4 + 3] = f.w;
    }
    __syncthreads();
#pragma unroll
    for (int i = 0; i < 4; ++i) {
        int n = tr + i * 16;
        ushort4 h;
        h.x = f2h(tile[tc4 + 0][n]);
        h.y = f2h(tile[tc4 + 1][n]);
        h.z = f2h(tile[tc4 + 2][n]);
        h.w = f2h(tile[tc4 + 3][n]);
        *(ushort4*)&Wth[(size_t)(n0 + n) * K + k0 + tc4] = h;
    }
}

__global__ __launch_bounds__(256)
void prep_w(const float* __restrict__ x, const float* __restrict__ w_attn,
            const float* __restrict__ w_proj, ushort_t* __restrict__ xh,
            ushort_t* __restrict__ wth, ushort_t* __restrict__ wtp) {
    __shared__ float tile[64][65];
    const int blk = blockIdx.x;
    const int tid = threadIdx.x;
    if (blk < 4096) {
        int idx = blk * 256 + tid;
        float4 f = ((const float4*)x)[idx];
        ushort4 h;
        h.x = f2h(f.x); h.y = f2h(f.y); h.z = f2h(f.z); h.w = f2h(f.w);
        ((ushort4*)xh)[idx] = h;
    } else if (blk < 4096 + 768) {
        int sub = blk - 4096;                  // w_attn: N=3C (48 n-tiles), K=C (16)
        convT_body(w_attn, wth, 3 * C_, C_, sub % 48, sub / 48, tid, tile);
    } else {
        int sub = blk - 4864;                  // w_proj: N=C (16), K=C (16)
        convT_body(w_proj, wtp, C_, C_, sub % 16, sub / 16, tid, tile);
    }
}

// ---------------------------------------------------------------------------
// fp16x1 MFMA GEMM with SWAPPED operands: acc = mfma(bf, af) puts the M-row
// on l16 and 4 CONSECUTIVE N-cols on (quad,r) -- packed 8B/16B stores.
// HALF_OUT: fp16 out, columns < qcols pre-scaled by qscale (Q plane).
// ---------------------------------------------------------------------------
template <bool HALF_OUT>
__global__ __launch_bounds__(256)
void gemm1(const ushort_t* __restrict__ Ah, const ushort_t* __restrict__ Bh,
           const float* __restrict__ bias, void* __restrict__ Cout,
           int M, int N, int K, int qcols, float qscale) {
    __shared__ ushort_t Lds[2 * 2 * 128 * 32];   // [plane][sub][row][32]

    const int tid = threadIdx.x;
    const int w = tid >> 6;
    const int lane = tid & 63;
    const int l16 = lane & 15;
    const int quad = lane >> 4;
    const int row0 = blockIdx.y * 128, col0 = blockIdx.x * 128;
    const int wr = w >> 1, wc = w & 1;

    const ushort_t* gb[8];
    ushort_t* lb[8];
#pragma unroll
    for (int j = 0; j < 8; ++j) {
        int q = j * 4 + w;
        int plane = q >> 4;
        int cc = q & 15;
        int sub = cc & 1;
        int r = (cc >> 1) * 16 + (lane >> 2);
        const ushort_t* src = plane ? Bh : Ah;
        int tb = plane ? col0 : row0;
        gb[j] = src + (size_t)(tb + r) * K + sub * 32 + (lane & 3) * 8;
        lb[j] = &Lds[plane * 8192 + sub * 4096 + r * 32 + (lane & 3) * 8];
    }

    f32x4 acc[4][4] = {};

    for (int k0 = 0; k0 < K; k0 += 64) {
        __syncthreads();
#pragma unroll
        for (int j = 0; j < 8; ++j)
            gload_lds16(gb[j] + k0, lb[j]);
        __syncthreads();

#pragma unroll
        for (int kk = 0; kk < 2; ++kk) {
            h16x8 af[4], bf[4];
#pragma unroll
            for (int mi = 0; mi < 4; ++mi)
                af[mi] = *(const h16x8*)&Lds[kk * 4096 + (wr * 64 + mi * 16 + l16) * 32 + quad * 8];
#pragma unroll
            for (int ni = 0; ni < 4; ++ni)
                bf[ni] = *(const h16x8*)&Lds[8192 + kk * 4096 + (wc * 64 + ni * 16 + l16) * 32 + quad * 8];
#pragma unroll
            for (int mi = 0; mi < 4; ++mi)
#pragma unroll
                for (int ni = 0; ni < 4; ++ni)
                    acc[mi][ni] = __builtin_amdgcn_mfma_f32_16x16x32_f16(bf[ni], af[mi], acc[mi][ni], 0, 0, 0);
        }
    }

    // block-uniform output scale (Q plane cols < qcols)
    const float osc = (HALF_OUT && col0 < qcols) ? qscale : 1.0f;

#pragma unroll
    for (int mi = 0; mi < 4; ++mi) {
        int row = row0 + wr * 64 + mi * 16 + l16;
#pragma unroll
        for (int ni = 0; ni < 4; ++ni) {
            int colb = col0 + wc * 64 + ni * 16 + quad * 4;
            float4 bs = *(const float4*)&bias[colb];
            float v0 = acc[mi][ni][0] + bs.x;
            float v1 = acc[mi][ni][1] + bs.y;
            float v2 = acc[mi][ni][2] + bs.z;
            float v3 = acc[mi][ni][3] + bs.w;
            if (HALF_OUT) {
                ushort4 pk;
                pk.x = f2h(v0 * osc); pk.y = f2h(v1 * osc);
                pk.z = f2h(v2 * osc); pk.w = f2h(v3 * osc);
                *(ushort4*)&((ushort_t*)Cout)[(size_t)row * N + colb] = pk;
            } else {
                float4 pk = make_float4(v0, v1, v2, v3);
                *(float4*)&((float*)Cout)[(size_t)row * N + colb] = pk;
            }
        }
    }
}

// ---------------------------------------------------------------------------
// zmax stage 1: per (b, t-chunk, c-tile) partial max over 128 t's.
// ---------------------------------------------------------------------------
__global__ __launch_bounds__(256)
void zmax_part(const ushort_t* __restrict__ qkvh, const float* __restrict__ p_param,
               float* __restrict__ zpart) {
    const int tch = blockIdx.x & 15;
    const int ctile = (blockIdx.x >> 4) & 15;
    const int b = blockIdx.x >> 8;
    const int col = threadIdx.x & 63;
    const int r = threadIdx.x >> 6;                 // 0..3
    const int c = ctile * 64 + col;

    const float p = clamp_p(p_param[c]);
    const ushort_t* vp = qkvh + (size_t)b * T_ * 3 * C_
                       + (size_t)(tch * 128) * 3 * C_ + 2 * C_ + c;

    float lm = -INFINITY;
    for (int t = r; t < 128; t += 4) {
        float v = h2f(vp[(size_t)t * 3 * C_]);
        float z = p * __logf(fmaxf(fabsf(v + SHIFT_), V_MIN_));
        lm = fmaxf(lm, z);
    }
    __shared__ float red[4][64];
    red[r][col] = lm;
    __syncthreads();
    if (threadIdx.x < 64) {
        float m = fmaxf(fmaxf(red[0][threadIdx.x], red[1][threadIdx.x]),
                        fmaxf(red[2][threadIdx.x], red[3][threadIdx.x]));
        zpart[((size_t)b * 16 + tch) * C_ + ctile * 64 + threadIdx.x] = m;
    }
}

// ---------------------------------------------------------------------------
// prep_kv: per (b,h,t-tile). Prologue folds the zmax finalization.
// K: dense fp16 swizzled copy (load-bearing; R6 measured +20us without it).
// V: GeM transform, transpose via LDS with k-axis bit-permutation
// pi(t) = [b5][b3b2][b4][b1b0] (matches in-register P layout), swizzled.
// ---------------------------------------------------------------------------
__global__ __launch_bounds__(256)
void prep_kv(const ushort_t* __restrict__ qkvh, const float* __restrict__ p_param,
             const float* __restrict__ zpart, float* __restrict__ zmax,
             ushort_t* __restrict__ kbf, ushort_t* __restrict__ vtbf) {
    __shared__ ushort_t VtL[64 * 72];
    __shared__ float zm_l[64];

    const int blk = blockIdx.x;
    const int tt = blk & 31;
    const int bh = blk >> 5;
    const int b = bh >> 4;
    const int h = bh & 15;
    const int t0 = tt * 64;

    const int tl = threadIdx.x >> 2;
    const int c0 = (threadIdx.x & 3) * 16;
    const int g0 = c0 >> 3;
    // pi(t): bits [b5][b3b2][b4][b1b0]
    const int ptl = ((tl >> 5) & 1) * 32 + ((tl >> 2) & 3) * 8
                  + ((tl >> 4) & 1) * 4 + (tl & 3);

    // ---- zmax finalize for this head's 64 channels ----
    if (threadIdx.x < 64) {
        int c = h * D_ + threadIdx.x;
        float m = -INFINITY;
#pragma unroll
        for (int ch = 0; ch < 16; ++ch)
            m = fmaxf(m, zpart[((size_t)b * 16 + ch) * C_ + c]);
        zm_l[threadIdx.x] = m;
        zmax[b * C_ + c] = m;
    }
    __syncthreads();

    const size_t rowbase = (size_t)(b * T_ + t0 + tl) * 3 * C_ + h * D_;

    // ---- K: dense swizzled copy (already fp16) ----
    {
        const ushort_t* ksrc = qkvh + rowbase + C_ + c0;
        s16x8 k0v = *(const s16x8*)&ksrc[0];
        s16x8 k1v = *(const s16x8*)&ksrc[8];
        size_t krow = ((size_t)bh * T_ + t0 + tl) * 64;
        *(s16x8*)&kbf[krow + ((g0)     ^ (tl & 7)) * 8] = k0v;
        *(s16x8*)&kbf[krow + ((g0 + 1) ^ (tl & 7)) * 8] = k1v;
    }

    // ---- V: GeM transform, store at column pi(t) ----
    {
        const ushort_t* vsrc = qkvh + rowbase + 2 * C_ + c0;
        ushort_t tv[16];
        *(s16x8*)&tv[0] = *(const s16x8*)&vsrc[0];
        *(s16x8*)&tv[8] = *(const s16x8*)&vsrc[8];
#pragma unroll
        for (int q = 0; q < 16; ++q) {
            int j = c0 + q;
            float p = clamp_p(p_param[h * D_ + j]);
            float v = h2f(tv[q]);
            float z = p * __logf(fmaxf(fabsf(v + SHIFT_), V_MIN_));
            float val = __expf(z - zm_l[j]);
            VtL[j * 72 + ptl] = f2h(val);
        }
    }
    __syncthreads();
    {
        const int d = tl;
        s16x8 r0 = *(const s16x8*)&VtL[d * 72 + c0];
        s16x8 r1 = *(const s16x8*)&VtL[d * 72 + c0 + 8];
        size_t vbase = ((size_t)bh * 32 + tt) * 4096 + (size_t)d * 64;
        *(s16x8*)&vtbf[vbase + ((g0)     ^ (d & 7)) * 8] = r0;
        *(s16x8*)&vtbf[vbase + ((g0 + 1) ^ (d & 7)) * 8] = r1;
    }
}

// ---------------------------------------------------------------------------
// Attention helpers. SWAPPED QK^T (S^T = mfma(K,Q): q on l16, k on
// (nt,quad,r)) keeps P in registers; PV also swapped (O^T = mfma(V, P):
// q on l16, d on (quad,r)).
// ---------------------------------------------------------------------------
__device__ __forceinline__ void load_frag(h16x8 kf[2][4], const ushort_t* tile,
                                          int l16, int sg0, int sg1) {
#pragma unroll
    for (int nt = 0; nt < 4; ++nt) {
        kf[0][nt] = *(const h16x8*)&tile[(nt * 16 + l16) * 64 + sg0];
        kf[1][nt] = *(const h16x8*)&tile[(nt * 16 + l16) * 64 + sg1];
    }
}

__device__ __forceinline__ void tile_body2(const h16x8 qf[2][2], const h16x8 kf[2][4],
        const h16x8 vf[2][4], const h16x8 ones, bool diag, int l16, int quad, int qh,
        f32x4 O[2][4], f32x4 Ol[2]) {
#pragma unroll
    for (int m = 0; m < 2; ++m) {
        // ---- S^T = K Q^T : s[nt][r] = S[k=nt*16+quad*4+r][q=l16] ----
        f32x4 s[4] = {};
#pragma unroll
        for (int nt = 0; nt < 4; ++nt) {
            s[nt] = __builtin_amdgcn_mfma_f32_16x16x32_f16(kf[0][nt], qf[m][0], s[nt], 0, 0, 0);
            s[nt] = __builtin_amdgcn_mfma_f32_16x16x32_f16(kf[1][nt], qf[m][1], s[nt], 0, 0, 0);
        }

        // ---- causal mask (diag tile only): k on (nt,quad,r), q on l16 ----
        if (diag) {
            int row = qh * 32 + m * 16 + l16;            // q (tile-local)
#pragma unroll
            for (int nt = 0; nt < 4; ++nt)
#pragma unroll
                for (int r = 0; r < 4; ++r) {
                    int col = nt * 16 + quad * 4 + r;    // k (tile-local)
                    if (col > row) s[nt][r] = -3.0e38f;
                }
        }

        // ---- P = exp2(s), pack in-register into PV A-frags ----
        // pa[ks] element j = P at k' = ks*32 + quad*8 + j, j = (nt&1)*4 + r
#pragma unroll
        for (int ks = 0; ks < 2; ++ks) {
            ushort_t t8[8];
#pragma unroll
            for (int r = 0; r < 4; ++r) {
                t8[r]     = f2h(fast_exp2(s[2 * ks][r]));
                t8[4 + r] = f2h(fast_exp2(s[2 * ks + 1][r]));
            }
            h16x8 pa = *(const h16x8*)t8;
            // l row-sum, transposed: D[*][l16=q]
            Ol[m] = __builtin_amdgcn_mfma_f32_16x16x32_f16(ones, pa, Ol[m], 0, 0, 0);
            // O^T: D[(quad,r)=d][l16=q]
#pragma unroll
            for (int nt = 0; nt < 4; ++nt)
                O[m][nt] = __builtin_amdgcn_mfma_f32_16x16x32_f16(vf[ks][nt], pa, O[m][nt], 0, 0, 0);
        }
    }
}

// ---------------------------------------------------------------------------
// Flash attention + fused combine. One block per (bh, qt): 4 waves =
// (q-half, k-parity). kp0 publishes partials via LDS Osum[qh][d][q]; kp1
// merges + transforms into LDS Ytile; all 4 waves store full cache lines.
// __launch_bounds__(256, 4): VGPR fits in 128 -> 4 blocks/CU resident =
// entire 1024-block grid co-resident. R10 measured Occupancy 17.8% with
// (256,2) and everything else idle (Mfma 14%, VALU 21%, HBM 8%) -- the
// per-tile serial chain (QK^T -> exp2 -> f2h -> PV) needs more waves/SIMD
// to hide, and the resources allow exactly 2x.
// ---------------------------------------------------------------------------
__global__ __launch_bounds__(256, 4)
void attn_mfma(const ushort_t* __restrict__ qkvh,
               const ushort_t* __restrict__ kbf, const ushort_t* __restrict__ vtbf,
               const float* __restrict__ zmax, const float* __restrict__ p_param,
               ushort_t* __restrict__ yh) {
    __shared__ float Osum[2][64][33];
    __shared__ float Lsum[2][32];
    __shared__ float zm_l[64], ip_l[64];
    __shared__ ushort_t Ytile[64][72];

    const int tid = threadIdx.x;
    const int w = tid >> 6;
    const int lane = tid & 63;
    const int l16 = lane & 15;
    const int quad = lane >> 4;
    const int qh = w >> 1;        // q-half: local rows qh*32..+32
    const int kp = w & 1;         // k-tile parity

    const int qt = 31 - (blockIdx.x >> 5);   // heavy first
    const int bh = blockIdx.x & 31;          // same-bh blocks share an XCD (32%8==0)
    const int b = bh >> 4;
    const int h = bh & 15;
    const int q0 = qt * 64;

    // stage zmax and 1/clamp_p for this head's 64 channels (indexed by d)
    if (tid < 64) {
        int c = h * D_ + tid;
        zm_l[tid] = zmax[b * C_ + c];
        ip_l[tid] = 1.f / clamp_p(p_param[c]);
    }

    // swizzled group offsets for fragment reads (k-step 0/1)
    const int sg0 = ((0 + quad) ^ (l16 & 7)) * 8;
    const int sg1 = ((4 + quad) ^ (l16 & 7)) * 8;

    f32x4 O[2][4] = {};
    f32x4 Ol[2] = {};

    h16x8 ones;
#pragma unroll
    for (int i = 0; i < 8; ++i) ones[i] = (_Float16)1.0f;

    // ---- Q B-frags: direct fp16 loads (pre-scaled by log2e/8 in GEMM) ----
    h16x8 qf[2][2];
#pragma unroll
    for (int m = 0; m < 2; ++m) {
        const int qrow = q0 + qh * 32 + m * 16 + l16;
        const ushort_t* qrp = qkvh + (size_t)(b * T_ + qrow) * 3 * C_ + h * D_;
#pragma unroll
        for (int ks = 0; ks < 2; ++ks)
            qf[m][ks] = *(const h16x8*)&qrp[ks * 32 + quad * 8];
    }

    const ushort_t* khead = kbf + (size_t)bh * T_ * 64;
    const ushort_t* vhead = vtbf + (size_t)bh * 32 * 4096;

    if (kp <= qt) {
        h16x8 kfA[2][4], kfB[2][4], vfA[2][4], vfB[2][4];
        load_frag(kfA, khead + (size_t)kp * 4096, l16, sg0, sg1);
        load_frag(vfA, vhead + (size_t)kp * 4096, l16, sg0, sg1);

        for (int kt = kp; kt <= qt; kt += 4) {
            int ktB = (kt + 2 <= qt) ? kt + 2 : kt;   // dummy reload on tail
            load_frag(kfB, khead + (size_t)ktB * 4096, l16, sg0, sg1);
            load_frag(vfB, vhead + (size_t)ktB * 4096, l16, sg0, sg1);
            tile_body2(qf, kfA, vfA, ones, kt == qt, l16, quad, qh, O, Ol);
            if (kt + 2 > qt) break;
            int ktA = (kt + 4 <= qt) ? kt + 4 : kt + 2;
            load_frag(kfA, khead + (size_t)ktA * 4096, l16, sg0, sg1);
            load_frag(vfA, vhead + (size_t)ktA * 4096, l16, sg0, sg1);
            tile_body2(qf, kfB, vfB, ones, kt + 2 == qt, l16, quad, qh, O, Ol);
        }
    }

    // ---- merge k-parity partials: kp0 publishes; kp1 merges + transform ----
    if (kp == 0) {
#pragma unroll
        for (int m = 0; m < 2; ++m) {
#pragma unroll
            for (int nt = 0; nt < 4; ++nt)
#pragma unroll
                for (int r = 0; r < 4; ++r)
                    Osum[qh][nt * 16 + quad * 4 + r][m * 16 + l16] = O[m][nt][r];
            if (quad == 0) Lsum[qh][m * 16 + l16] = Ol[m][0];
        }
    }
    __syncthreads();
    if (kp == 1) {
#pragma unroll
        for (int m = 0; m < 2; ++m) {
            int ql = m * 16 + l16;                       // local q (0..31)
            float inv_den = 1.f / (Ol[m][0] + Lsum[qh][ql]);
#pragma unroll
            for (int nt = 0; nt < 4; ++nt) {
                ushort4 pk;
#pragma unroll
                for (int r = 0; r < 4; ++r) {
                    int d = nt * 16 + quad * 4 + r;
                    float mean = (O[m][nt][r] + Osum[qh][d][ql]) * inv_den;
                    float y = __expf((zm_l[d] + __logf(mean)) * ip_l[d]) - SHIFT_;
                    ((ushort_t*)&pk)[r] = f2h(y);
                }
                *(ushort4*)&Ytile[qh * 32 + ql][nt * 16 + quad * 4] = pk;
            }
        }
    }
    __syncthreads();

    // ---- cooperative full-line store: 64 rows x 128B, all 4 waves ----
#pragma unroll
    for (int it = 0; it < 2; ++it) {
        int c = it * 256 + tid;
        int row = c >> 3;
        int part = c & 7;
        s16x8 v = *(const s16x8*)&Ytile[row][part * 8];
        *(s16x8*)&yh[(size_t)(b * T_ + q0 + row) * C_ + h * D_ + part * 8] = v;
    }
}

// ---------------------------------------------------------------------------
extern "C" void kernel_launch(void* const* d_in, const int* in_sizes, int n_in,
                              void* d_out, int out_size, void* d_ws, size_t ws_size,
                              hipStream_t stream) {
    const float* x      = (const float*)d_in[0];
    const float* w_attn = (const float*)d_in[1];
    const float* b_attn = (const float*)d_in[2];
    const float* w_proj = (const float*)d_in[3];
    const float* b_proj = (const float*)d_in[4];
    const float* p_par  = (const float*)d_in[5];
    float* out = (float*)d_out;

    char* ws = (char*)d_ws;
    ushort_t* qkvh = (ushort_t*)ws;                           // M x 3C fp16
    ushort_t* xh   = qkvh + (size_t)M_ * 3 * C_;              // M x C fp16 (aliases yh)
    ushort_t* wth  = xh + (size_t)M_ * C_;                    // 3C x C fp16
    ushort_t* wtp  = wth + (size_t)3 * C_ * C_;               // C x C fp16
    float* zmax = (float*)(wtp + (size_t)C_ * C_);            // B x C
    ushort_t* kbf  = (ushort_t*)(zmax + B_ * C_);             // BH x T x 64 fp16
    ushort_t* vtbf = kbf + (size_t)B_ * H_ * T_ * 64;         // BH x 32 x 64 x 64 fp16
    float* zpart = (float*)(vtbf + (size_t)B_ * H_ * T_ * 64); // B x 16 x C

    // 1) fused: x -> fp16, w_attn/w_proj transposes -> fp16
    prep_w<<<4096 + 768 + 256, 256, 0, stream>>>(x, w_attn, w_proj, xh, wth, wtp);
    // 2) qkv = x @ w_attn + b_attn -> fp16 (Q plane pre-scaled by log2e/8)
    gemm1<true><<<dim3(3 * C_ / 128, M_ / 128), 256, 0, stream>>>(
        xh, wth, b_attn, qkvh, M_, 3 * C_, C_, C_, QS_);
    // 3) z_max partials over T per (b,c)
    zmax_part<<<B_ * 16 * 16, 256, 0, stream>>>(qkvh, p_par, zpart);
    // 4) prep K/V (zmax finalize folded in; writes zmax for attn)
    prep_kv<<<B_ * H_ * 32, 256, 0, stream>>>(qkvh, p_par, zpart, zmax, kbf, vtbf);
    // 5) MFMA flash attention + fused combine (4 blocks/CU co-resident)
    attn_mfma<<<B_ * H_ * (T_ / 64), 256, 0, stream>>>(qkvh, kbf, vtbf,
                                                       zmax, p_par, xh);
    // 6) out = y @ w_proj + b_proj (fp32 out, packed float4 stores)
    gemm1<false><<<dim3(C_ / 128, M_ / 128), 256, 0, stream>>>(
        xh, wtp, b_proj, out, M_, C_, C_, 0, 1.0f);
}

// Round 12
// 196.205 us; speedup vs baseline: 2.5959x; 2.5959x over previous
//
#include <hip/hip_runtime.h>
#include <hip/hip_bf16.h>
#include <math.h>

// Problem constants (fixed by setup_inputs)
constexpr int B_ = 2;
constexpr int T_ = 2048;
constexpr int C_ = 1024;
constexpr int H_ = 16;
constexpr int D_ = 64;       // head dim
constexpr int M_ = B_ * T_;  // 4096 rows
constexpr float SHIFT_ = 5.0f;
constexpr float P_MIN_ = 1e-4f;
constexpr float P_MAX_ = 1e3f;
constexpr float V_MIN_ = 1e-10f;
// Q is pre-scaled by log2e/8 in the GEMM epilogue; P = exp2(s) directly.
// Any uniform factor on P cancels exactly in mean = (P@V)/(P@1).
constexpr float QS_ = 0.125f * 1.4426950408889634f;

typedef __attribute__((ext_vector_type(8))) short s16x8;
typedef __attribute__((ext_vector_type(8))) _Float16 h16x8;
typedef __attribute__((ext_vector_type(4))) float f32x4;
typedef unsigned short ushort_t;

__device__ __forceinline__ float clamp_p(float pp) {
    float s = (pp >= 0.f) ? 1.f : -1.f;
    return s * fminf(fmaxf(fabsf(pp), P_MIN_), P_MAX_);
}

// fp32 <-> fp16 bits (RTNE)
__device__ __forceinline__ ushort_t f2h(float f) {
    _Float16 h = (_Float16)f;
    return __builtin_bit_cast(unsigned short, h);
}
__device__ __forceinline__ float h2f(ushort_t h) {
    return (float)__builtin_bit_cast(_Float16, h);
}

// 2^x via v_exp_f32
__device__ __forceinline__ float fast_exp2(float x) {
#if __has_builtin(__builtin_amdgcn_exp2f)
    return __builtin_amdgcn_exp2f(x);
#else
    return __expf(x * 0.6931471805599453f);
#endif
}

// async global->LDS, 16B per lane. LDS dest must be (wave-uniform base + lane*16).
__device__ __forceinline__ void gload_lds16(const void* g, void* l) {
    __builtin_amdgcn_global_load_lds(
        (const __attribute__((address_space(1))) unsigned int*)g,
        (__attribute__((address_space(3))) unsigned int*)l, 16, 0, 0);
}

// ---------------------------------------------------------------------------
// prep_w: fused input prep -- x -> fp16 (blocks 0..4095), w_attn transpose
// (blocks 4096..4863), w_proj transpose (blocks 4864..5119).
// ---------------------------------------------------------------------------
__device__ __forceinline__ void convT_body(const float* __restrict__ W,
                                           ushort_t* __restrict__ Wth,
                                           int N, int K, int bx, int by,
                                           int tid, float (*tile)[65]) {
    const int k0 = by * 64, n0 = bx * 64;
    const int tr = tid >> 4;
    const int tc4 = (tid & 15) * 4;
#pragma unroll
    for (int i = 0; i < 4; ++i) {
        float4 f = *(const float4*)&W[(size_t)(k0 + tr + i * 16) * N + n0 + tc4];
        tile[tr + i * 16][tc4 + 0] = f.x;
        tile[tr + i * 16][tc4 + 1] = f.y;
        tile[tr + i * 16][tc4 + 2] = f.z;
        tile[tr + i * 16][tc4 + 3] = f.w;
    }
    __syncthreads();
#pragma unroll
    for (int i = 0; i < 4; ++i) {
        int n = tr + i * 16;
        ushort4 h;
        h.x = f2h(tile[tc4 + 0][n]);
        h.y = f2h(tile[tc4 + 1][n]);
        h.z = f2h(tile[tc4 + 2][n]);
        h.w = f2h(tile[tc4 + 3][n]);
        *(ushort4*)&Wth[(size_t)(n0 + n) * K + k0 + tc4] = h;
    }
}

__global__ __launch_bounds__(256)
void prep_w(const float* __restrict__ x, const float* __restrict__ w_attn,
            const float* __restrict__ w_proj, ushort_t* __restrict__ xh,
            ushort_t* __restrict__ wth, ushort_t* __restrict__ wtp) {
    __shared__ float tile[64][65];
    const int blk = blockIdx.x;
    const int tid = threadIdx.x;
    if (blk < 4096) {
        int idx = blk * 256 + tid;
        float4 f = ((const float4*)x)[idx];
        ushort4 h;
        h.x = f2h(f.x); h.y = f2h(f.y); h.z = f2h(f.z); h.w = f2h(f.w);
        ((ushort4*)xh)[idx] = h;
    } else if (blk < 4096 + 768) {
        int sub = blk - 4096;                  // w_attn: N=3C (48 n-tiles), K=C (16)
        convT_body(w_attn, wth, 3 * C_, C_, sub % 48, sub / 48, tid, tile);
    } else {
        int sub = blk - 4864;                  // w_proj: N=C (16), K=C (16)
        convT_body(w_proj, wtp, C_, C_, sub % 16, sub / 16, tid, tile);
    }
}

// ---------------------------------------------------------------------------
// fp16x1 MFMA GEMM with SWAPPED operands: acc = mfma(bf, af) puts the M-row
// on l16 and 4 CONSECUTIVE N-cols on (quad,r) -- packed 8B/16B stores.
// HALF_OUT: fp16 out, columns < qcols pre-scaled by qscale (Q plane).
// ---------------------------------------------------------------------------
template <bool HALF_OUT>
__global__ __launch_bounds__(256)
void gemm1(const ushort_t* __restrict__ Ah, const ushort_t* __restrict__ Bh,
           const float* __restrict__ bias, void* __restrict__ Cout,
           int M, int N, int K, int qcols, float qscale) {
    __shared__ ushort_t Lds[2 * 2 * 128 * 32];   // [plane][sub][row][32]

    const int tid = threadIdx.x;
    const int w = tid >> 6;
    const int lane = tid & 63;
    const int l16 = lane & 15;
    const int quad = lane >> 4;
    const int row0 = blockIdx.y * 128, col0 = blockIdx.x * 128;
    const int wr = w >> 1, wc = w & 1;

    const ushort_t* gb[8];
    ushort_t* lb[8];
#pragma unroll
    for (int j = 0; j < 8; ++j) {
        int q = j * 4 + w;
        int plane = q >> 4;
        int cc = q & 15;
        int sub = cc & 1;
        int r = (cc >> 1) * 16 + (lane >> 2);
        const ushort_t* src = plane ? Bh : Ah;
        int tb = plane ? col0 : row0;
        gb[j] = src + (size_t)(tb + r) * K + sub * 32 + (lane & 3) * 8;
        lb[j] = &Lds[plane * 8192 + sub * 4096 + r * 32 + (lane & 3) * 8];
    }

    f32x4 acc[4][4] = {};

    for (int k0 = 0; k0 < K; k0 += 64) {
        __syncthreads();
#pragma unroll
        for (int j = 0; j < 8; ++j)
            gload_lds16(gb[j] + k0, lb[j]);
        __syncthreads();

#pragma unroll
        for (int kk = 0; kk < 2; ++kk) {
            h16x8 af[4], bf[4];
#pragma unroll
            for (int mi = 0; mi < 4; ++mi)
                af[mi] = *(const h16x8*)&Lds[kk * 4096 + (wr * 64 + mi * 16 + l16) * 32 + quad * 8];
#pragma unroll
            for (int ni = 0; ni < 4; ++ni)
                bf[ni] = *(const h16x8*)&Lds[8192 + kk * 4096 + (wc * 64 + ni * 16 + l16) * 32 + quad * 8];
#pragma unroll
            for (int mi = 0; mi < 4; ++mi)
#pragma unroll
                for (int ni = 0; ni < 4; ++ni)
                    acc[mi][ni] = __builtin_amdgcn_mfma_f32_16x16x32_f16(bf[ni], af[mi], acc[mi][ni], 0, 0, 0);
        }
    }

    // block-uniform output scale (Q plane cols < qcols)
    const float osc = (HALF_OUT && col0 < qcols) ? qscale : 1.0f;

#pragma unroll
    for (int mi = 0; mi < 4; ++mi) {
        int row = row0 + wr * 64 + mi * 16 + l16;
#pragma unroll
        for (int ni = 0; ni < 4; ++ni) {
            int colb = col0 + wc * 64 + ni * 16 + quad * 4;
            float4 bs = *(const float4*)&bias[colb];
            float v0 = acc[mi][ni][0] + bs.x;
            float v1 = acc[mi][ni][1] + bs.y;
            float v2 = acc[mi][ni][2] + bs.z;
            float v3 = acc[mi][ni][3] + bs.w;
            if (HALF_OUT) {
                ushort4 pk;
                pk.x = f2h(v0 * osc); pk.y = f2h(v1 * osc);
                pk.z = f2h(v2 * osc); pk.w = f2h(v3 * osc);
                *(ushort4*)&((ushort_t*)Cout)[(size_t)row * N + colb] = pk;
            } else {
                float4 pk = make_float4(v0, v1, v2, v3);
                *(float4*)&((float*)Cout)[(size_t)row * N + colb] = pk;
            }
        }
    }
}

// ---------------------------------------------------------------------------
// zmax stage 1: per (b, t-chunk, c-tile) partial max over 128 t's.
// ---------------------------------------------------------------------------
__global__ __launch_bounds__(256)
void zmax_part(const ushort_t* __restrict__ qkvh, const float* __restrict__ p_param,
               float* __restrict__ zpart) {
    const int tch = blockIdx.x & 15;
    const int ctile = (blockIdx.x >> 4) & 15;
    const int b = blockIdx.x >> 8;
    const int col = threadIdx.x & 63;
    const int r = threadIdx.x >> 6;                 // 0..3
    const int c = ctile * 64 + col;

    const float p = clamp_p(p_param[c]);
    const ushort_t* vp = qkvh + (size_t)b * T_ * 3 * C_
                       + (size_t)(tch * 128) * 3 * C_ + 2 * C_ + c;

    float lm = -INFINITY;
    for (int t = r; t < 128; t += 4) {
        float v = h2f(vp[(size_t)t * 3 * C_]);
        float z = p * __logf(fmaxf(fabsf(v + SHIFT_), V_MIN_));
        lm = fmaxf(lm, z);
    }
    __shared__ float red[4][64];
    red[r][col] = lm;
    __syncthreads();
    if (threadIdx.x < 64) {
        float m = fmaxf(fmaxf(red[0][threadIdx.x], red[1][threadIdx.x]),
                        fmaxf(red[2][threadIdx.x], red[3][threadIdx.x]));
        zpart[((size_t)b * 16 + tch) * C_ + ctile * 64 + threadIdx.x] = m;
    }
}

// ---------------------------------------------------------------------------
// prep_kv: per (b,h,t-tile). Prologue folds the zmax finalization.
// K: dense fp16 swizzled copy (load-bearing; R6 measured +20us without it).
// V: GeM transform, transpose via LDS with k-axis bit-permutation
// pi(t) = [b5][b3b2][b4][b1b0] (matches in-register P layout), swizzled.
// ---------------------------------------------------------------------------
__global__ __launch_bounds__(256)
void prep_kv(const ushort_t* __restrict__ qkvh, const float* __restrict__ p_param,
             const float* __restrict__ zpart, float* __restrict__ zmax,
             ushort_t* __restrict__ kbf, ushort_t* __restrict__ vtbf) {
    __shared__ ushort_t VtL[64 * 72];
    __shared__ float zm_l[64];

    const int blk = blockIdx.x;
    const int tt = blk & 31;
    const int bh = blk >> 5;
    const int b = bh >> 4;
    const int h = bh & 15;
    const int t0 = tt * 64;

    const int tl = threadIdx.x >> 2;
    const int c0 = (threadIdx.x & 3) * 16;
    const int g0 = c0 >> 3;
    // pi(t): bits [b5][b3b2][b4][b1b0]
    const int ptl = ((tl >> 5) & 1) * 32 + ((tl >> 2) & 3) * 8
                  + ((tl >> 4) & 1) * 4 + (tl & 3);

    // ---- zmax finalize for this head's 64 channels ----
    if (threadIdx.x < 64) {
        int c = h * D_ + threadIdx.x;
        float m = -INFINITY;
#pragma unroll
        for (int ch = 0; ch < 16; ++ch)
            m = fmaxf(m, zpart[((size_t)b * 16 + ch) * C_ + c]);
        zm_l[threadIdx.x] = m;
        zmax[b * C_ + c] = m;
    }
    __syncthreads();

    const size_t rowbase = (size_t)(b * T_ + t0 + tl) * 3 * C_ + h * D_;

    // ---- K: dense swizzled copy (already fp16) ----
    {
        const ushort_t* ksrc = qkvh + rowbase + C_ + c0;
        s16x8 k0v = *(const s16x8*)&ksrc[0];
        s16x8 k1v = *(const s16x8*)&ksrc[8];
        size_t krow = ((size_t)bh * T_ + t0 + tl) * 64;
        *(s16x8*)&kbf[krow + ((g0)     ^ (tl & 7)) * 8] = k0v;
        *(s16x8*)&kbf[krow + ((g0 + 1) ^ (tl & 7)) * 8] = k1v;
    }

    // ---- V: GeM transform, store at column pi(t) ----
    {
        const ushort_t* vsrc = qkvh + rowbase + 2 * C_ + c0;
        ushort_t tv[16];
        *(s16x8*)&tv[0] = *(const s16x8*)&vsrc[0];
        *(s16x8*)&tv[8] = *(const s16x8*)&vsrc[8];
#pragma unroll
        for (int q = 0; q < 16; ++q) {
            int j = c0 + q;
            float p = clamp_p(p_param[h * D_ + j]);
            float v = h2f(tv[q]);
            float z = p * __logf(fmaxf(fabsf(v + SHIFT_), V_MIN_));
            float val = __expf(z - zm_l[j]);
            VtL[j * 72 + ptl] = f2h(val);
        }
    }
    __syncthreads();
    {
        const int d = tl;
        s16x8 r0 = *(const s16x8*)&VtL[d * 72 + c0];
        s16x8 r1 = *(const s16x8*)&VtL[d * 72 + c0 + 8];
        size_t vbase = ((size_t)bh * 32 + tt) * 4096 + (size_t)d * 64;
        *(s16x8*)&vtbf[vbase + ((g0)     ^ (d & 7)) * 8] = r0;
        *(s16x8*)&vtbf[vbase + ((g0 + 1) ^ (d & 7)) * 8] = r1;
    }
}

// ---------------------------------------------------------------------------
// Attention helpers. SWAPPED QK^T (S^T = mfma(K,Q): q on l16, k on
// (nt,quad,r)) keeps P in registers; PV also swapped (O^T = mfma(V, P):
// q on l16, d on (quad,r)).
// ---------------------------------------------------------------------------
__device__ __forceinline__ void load_frag(h16x8 kf[2][4], const ushort_t* tile,
                                          int l16, int sg0, int sg1) {
#pragma unroll
    for (int nt = 0; nt < 4; ++nt) {
        kf[0][nt] = *(const h16x8*)&tile[(nt * 16 + l16) * 64 + sg0];
        kf[1][nt] = *(const h16x8*)&tile[(nt * 16 + l16) * 64 + sg1];
    }
}

__device__ __forceinline__ void tile_body2(const h16x8 qf[2][2], const h16x8 kf[2][4],
        const h16x8 vf[2][4], const h16x8 ones, bool diag, int l16, int quad, int qh,
        f32x4 O[2][4], f32x4 Ol[2]) {
#pragma unroll
    for (int m = 0; m < 2; ++m) {
        // ---- S^T = K Q^T : s[nt][r] = S[k=nt*16+quad*4+r][q=l16] ----
        f32x4 s[4] = {};
#pragma unroll
        for (int nt = 0; nt < 4; ++nt) {
            s[nt] = __builtin_amdgcn_mfma_f32_16x16x32_f16(kf[0][nt], qf[m][0], s[nt], 0, 0, 0);
            s[nt] = __builtin_amdgcn_mfma_f32_16x16x32_f16(kf[1][nt], qf[m][1], s[nt], 0, 0, 0);
        }

        // ---- causal mask (diag tile only): k on (nt,quad,r), q on l16 ----
        if (diag) {
            int row = qh * 32 + m * 16 + l16;            // q (tile-local)
#pragma unroll
            for (int nt = 0; nt < 4; ++nt)
#pragma unroll
                for (int r = 0; r < 4; ++r) {
                    int col = nt * 16 + quad * 4 + r;    // k (tile-local)
                    if (col > row) s[nt][r] = -3.0e38f;
                }
        }

        // ---- P = exp2(s), pack in-register into PV A-frags ----
        // pa[ks] element j = P at k' = ks*32 + quad*8 + j, j = (nt&1)*4 + r
#pragma unroll
        for (int ks = 0; ks < 2; ++ks) {
            ushort_t t8[8];
#pragma unroll
            for (int r = 0; r < 4; ++r) {
                t8[r]     = f2h(fast_exp2(s[2 * ks][r]));
                t8[4 + r] = f2h(fast_exp2(s[2 * ks + 1][r]));
            }
            h16x8 pa = *(const h16x8*)t8;
            // l row-sum, transposed: D[*][l16=q]
            Ol[m] = __builtin_amdgcn_mfma_f32_16x16x32_f16(ones, pa, Ol[m], 0, 0, 0);
            // O^T: D[(quad,r)=d][l16=q]
#pragma unroll
            for (int nt = 0; nt < 4; ++nt)
                O[m][nt] = __builtin_amdgcn_mfma_f32_16x16x32_f16(vf[ks][nt], pa, O[m][nt], 0, 0, 0);
        }
    }
}

// ---------------------------------------------------------------------------
// Flash attention + fused combine. One block per (bh, qt): 4 waves =
// (q-half, k-parity). K frags double-buffered ACROSS tiles (consumed at
// tile start); V frags SINGLE-buffered -- V isn't consumed until after
// QK^T + exp2 (~400 cyc), so a tile-start load hides its L2 latency
// WITHIN the tile. This cuts 32 VGPRs vs R10 so a 3rd block/CU can fit
// in the unified VGPR+AGPR file naturally (no launch-bounds coercion --
// R11's forced (256,4) halved the register cap and spilled to scratch).
// ---------------------------------------------------------------------------
__global__ __launch_bounds__(256, 2)
void attn_mfma(const ushort_t* __restrict__ qkvh,
               const ushort_t* __restrict__ kbf, const ushort_t* __restrict__ vtbf,
               const float* __restrict__ zmax, const float* __restrict__ p_param,
               ushort_t* __restrict__ yh) {
    __shared__ float Osum[2][64][33];
    __shared__ float Lsum[2][32];
    __shared__ float zm_l[64], ip_l[64];
    __shared__ ushort_t Ytile[64][72];

    const int tid = threadIdx.x;
    const int w = tid >> 6;
    const int lane = tid & 63;
    const int l16 = lane & 15;
    const int quad = lane >> 4;
    const int qh = w >> 1;        // q-half: local rows qh*32..+32
    const int kp = w & 1;         // k-tile parity

    const int qt = 31 - (blockIdx.x >> 5);   // heavy first
    const int bh = blockIdx.x & 31;          // same-bh blocks share an XCD (32%8==0)
    const int b = bh >> 4;
    const int h = bh & 15;
    const int q0 = qt * 64;

    // stage zmax and 1/clamp_p for this head's 64 channels (indexed by d)
    if (tid < 64) {
        int c = h * D_ + tid;
        zm_l[tid] = zmax[b * C_ + c];
        ip_l[tid] = 1.f / clamp_p(p_param[c]);
    }

    // swizzled group offsets for fragment reads (k-step 0/1)
    const int sg0 = ((0 + quad) ^ (l16 & 7)) * 8;
    const int sg1 = ((4 + quad) ^ (l16 & 7)) * 8;

    f32x4 O[2][4] = {};
    f32x4 Ol[2] = {};

    h16x8 ones;
#pragma unroll
    for (int i = 0; i < 8; ++i) ones[i] = (_Float16)1.0f;

    // ---- Q B-frags: direct fp16 loads (pre-scaled by log2e/8 in GEMM) ----
    h16x8 qf[2][2];
#pragma unroll
    for (int m = 0; m < 2; ++m) {
        const int qrow = q0 + qh * 32 + m * 16 + l16;
        const ushort_t* qrp = qkvh + (size_t)(b * T_ + qrow) * 3 * C_ + h * D_;
#pragma unroll
        for (int ks = 0; ks < 2; ++ks)
            qf[m][ks] = *(const h16x8*)&qrp[ks * 32 + quad * 8];
    }

    const ushort_t* khead = kbf + (size_t)bh * T_ * 64;
    const ushort_t* vhead = vtbf + (size_t)bh * 32 * 4096;

    if (kp <= qt) {
        h16x8 kfA[2][4], kfB[2][4], vf[2][4];
        load_frag(kfA, khead + (size_t)kp * 4096, l16, sg0, sg1);

        for (int kt = kp; kt <= qt; kt += 4) {
            // V for current tile: issued now, consumed after QK^T+exp (hidden)
            load_frag(vf, vhead + (size_t)kt * 4096, l16, sg0, sg1);
            int ktB = (kt + 2 <= qt) ? kt + 2 : kt;   // dummy reload on tail
            load_frag(kfB, khead + (size_t)ktB * 4096, l16, sg0, sg1);
            tile_body2(qf, kfA, vf, ones, kt == qt, l16, quad, qh, O, Ol);
            if (kt + 2 > qt) break;
            load_frag(vf, vhead + (size_t)(kt + 2) * 4096, l16, sg0, sg1);
            int ktA = (kt + 4 <= qt) ? kt + 4 : kt + 2;
            load_frag(kfA, khead + (size_t)ktA * 4096, l16, sg0, sg1);
            tile_body2(qf, kfB, vf, ones, kt + 2 == qt, l16, quad, qh, O, Ol);
        }
    }

    // ---- merge k-parity partials: kp0 publishes; kp1 merges + transform ----
    if (kp == 0) {
#pragma unroll
        for (int m = 0; m < 2; ++m) {
#pragma unroll
            for (int nt = 0; nt < 4; ++nt)
#pragma unroll
                for (int r = 0; r < 4; ++r)
                    Osum[qh][nt * 16 + quad * 4 + r][m * 16 + l16] = O[m][nt][r];
            if (quad == 0) Lsum[qh][m * 16 + l16] = Ol[m][0];
        }
    }
    __syncthreads();
    if (kp == 1) {
#pragma unroll
        for (int m = 0; m < 2; ++m) {
            int ql = m * 16 + l16;                       // local q (0..31)
            float inv_den = 1.f / (Ol[m][0] + Lsum[qh][ql]);
#pragma unroll
            for (int nt = 0; nt < 4; ++nt) {
                ushort4 pk;
#pragma unroll
                for (int r = 0; r < 4; ++r) {
                    int d = nt * 16 + quad * 4 + r;
                    float mean = (O[m][nt][r] + Osum[qh][d][ql]) * inv_den;
                    float y = __expf((zm_l[d] + __logf(mean)) * ip_l[d]) - SHIFT_;
                    ((ushort_t*)&pk)[r] = f2h(y);
                }
                *(ushort4*)&Ytile[qh * 32 + ql][nt * 16 + quad * 4] = pk;
            }
        }
    }
    __syncthreads();

    // ---- cooperative full-line store: 64 rows x 128B, all 4 waves ----
#pragma unroll
    for (int it = 0; it < 2; ++it) {
        int c = it * 256 + tid;
        int row = c >> 3;
        int part = c & 7;
        s16x8 v = *(const s16x8*)&Ytile[row][part * 8];
        *(s16x8*)&yh[(size_t)(b * T_ + q0 + row) * C_ + h * D_ + part * 8] = v;
    }
}

// ---------------------------------------------------------------------------
extern "C" void kernel_launch(void* const* d_in, const int* in_sizes, int n_in,
                              void* d_out, int out_size, void* d_ws, size_t ws_size,
                              hipStream_t stream) {
    const float* x      = (const float*)d_in[0];
    const float* w_attn = (const float*)d_in[1];
    const float* b_attn = (const float*)d_in[2];
    const float* w_proj = (const float*)d_in[3];
    const float* b_proj = (const float*)d_in[4];
    const float* p_par  = (const float*)d_in[5];
    float* out = (float*)d_out;

    char* ws = (char*)d_ws;
    ushort_t* qkvh = (ushort_t*)ws;                           // M x 3C fp16
    ushort_t* xh   = qkvh + (size_t)M_ * 3 * C_;              // M x C fp16 (aliases yh)
    ushort_t* wth  = xh + (size_t)M_ * C_;                    // 3C x C fp16
    ushort_t* wtp  = wth + (size_t)3 * C_ * C_;               // C x C fp16
    float* zmax = (float*)(wtp + (size_t)C_ * C_);            // B x C
    ushort_t* kbf  = (ushort_t*)(zmax + B_ * C_);             // BH x T x 64 fp16
    ushort_t* vtbf = kbf + (size_t)B_ * H_ * T_ * 64;         // BH x 32 x 64 x 64 fp16
    float* zpart = (float*)(vtbf + (size_t)B_ * H_ * T_ * 64); // B x 16 x C

    // 1) fused: x -> fp16, w_attn/w_proj transposes -> fp16
    prep_w<<<4096 + 768 + 256, 256, 0, stream>>>(x, w_attn, w_proj, xh, wth, wtp);
    // 2) qkv = x @ w_attn + b_attn -> fp16 (Q plane pre-scaled by log2e/8)
    gemm1<true><<<dim3(3 * C_ / 128, M_ / 128), 256, 0, stream>>>(
        xh, wth, b_attn, qkvh, M_, 3 * C_, C_, C_, QS_);
    // 3) z_max partials over T per (b,c)
    zmax_part<<<B_ * 16 * 16, 256, 0, stream>>>(qkvh, p_par, zpart);
    // 4) prep K/V (zmax finalize folded in; writes zmax for attn)
    prep_kv<<<B_ * H_ * 32, 256, 0, stream>>>(qkvh, p_par, zpart, zmax, kbf, vtbf);
    // 5) MFMA flash attention + fused combine (single-buffered V, lower VGPR)
    attn_mfma<<<B_ * H_ * (T_ / 64), 256, 0, stream>>>(qkvh, kbf, vtbf,
                                                       zmax, p_par, xh);
    // 6) out = y @ w_proj + b_proj (fp32 out, packed float4 stores)
    gemm1<false><<<dim3(C_ / 128, M_ / 128), 256, 0, stream>>>(
        xh, wtp, b_proj, out, M_, C_, C_, 0, 1.0f);
}